// Round 1
// baseline (237.202 us; speedup 1.0000x reference)
//
#include <hip/hip_runtime.h>

#define BB 32768
#define FF 16
#define HH 64
#define OO 32
#define EE 16

// ---------------- Phase 1: per-feature subnets -> tok [F][B][E] ----------------
__global__ __launch_bounds__(256) void spinn_subnet_kernel(
    const float* __restrict__ x,
    const float* __restrict__ W1, const float* __restrict__ b1,
    const float* __restrict__ W2, const float* __restrict__ b2,
    const float* __restrict__ W3, const float* __restrict__ b3,
    const float* __restrict__ Wp, const float* __restrict__ bp,
    float* __restrict__ tok)
{
    __shared__ __align__(16) float sW2[HH*HH];   // 16 KB
    __shared__ __align__(16) float sW3[HH*OO];   // 8 KB
    __shared__ __align__(16) float sWp[OO*EE];   // 2 KB
    __shared__ float sW1[HH], sB1[HH], sB2[HH], sB3[OO], sBp[EE];

    const int f = blockIdx.y;
    const int t = threadIdx.x;

    // cooperative staging (all loads coalesced float4)
    {
        const float4* s2 = (const float4*)(W2 + f*HH*HH);
        float4* d2 = (float4*)sW2;
        #pragma unroll
        for (int i = 0; i < 4; ++i) d2[t + 256*i] = s2[t + 256*i];
        const float4* s3 = (const float4*)(W3 + f*HH*OO);
        float4* d3 = (float4*)sW3;
        #pragma unroll
        for (int i = 0; i < 2; ++i) d3[t + 256*i] = s3[t + 256*i];
        if (t < OO*EE/4) ((float4*)sWp)[t] = ((const float4*)Wp)[t];
        if (t < HH) { sW1[t] = W1[f*HH + t]; sB1[t] = b1[f*HH + t]; sB2[t] = b2[f*HH + t]; }
        if (t < OO) sB3[t] = b3[f*OO + t];
        if (t < EE) sBp[t] = bp[t];
    }
    __syncthreads();

    const int b = blockIdx.x * 256 + t;
    const float xv = x[b*FF + f];

    // layer 2 accumulators; h1 recomputed per j (no runtime-indexed reg array)
    float h2[HH];
    #pragma unroll
    for (int k = 0; k < HH; ++k) h2[k] = sB2[k];

    for (int j = 0; j < HH; ++j) {   // rolled: tiny code, LDS reads are uniform broadcasts
        float h1 = fmaf(xv, sW1[j], sB1[j]);
        h1 = (h1 >= 0.f) ? h1 : 0.01f*h1;
        const float4* wr = (const float4*)(sW2 + j*HH);
        #pragma unroll
        for (int k4 = 0; k4 < HH/4; ++k4) {
            float4 w = wr[k4];
            h2[4*k4+0] = fmaf(h1, w.x, h2[4*k4+0]);
            h2[4*k4+1] = fmaf(h1, w.y, h2[4*k4+1]);
            h2[4*k4+2] = fmaf(h1, w.z, h2[4*k4+2]);
            h2[4*k4+3] = fmaf(h1, w.w, h2[4*k4+3]);
        }
    }
    #pragma unroll
    for (int k = 0; k < HH; ++k) { float v = h2[k]; h2[k] = (v >= 0.f) ? v : 0.01f*v; }

    // layer 3 (fully unrolled so h2[j] is statically indexed)
    float to_[OO];
    #pragma unroll
    for (int o = 0; o < OO; ++o) to_[o] = sB3[o];
    #pragma unroll
    for (int j = 0; j < HH; ++j) {
        const float hv = h2[j];
        const float4* wr = (const float4*)(sW3 + j*OO);
        #pragma unroll
        for (int o4 = 0; o4 < OO/4; ++o4) {
            float4 w = wr[o4];
            to_[4*o4+0] = fmaf(hv, w.x, to_[4*o4+0]);
            to_[4*o4+1] = fmaf(hv, w.y, to_[4*o4+1]);
            to_[4*o4+2] = fmaf(hv, w.z, to_[4*o4+2]);
            to_[4*o4+3] = fmaf(hv, w.w, to_[4*o4+3]);
        }
    }

    // proj O->E
    float te[EE];
    #pragma unroll
    for (int e = 0; e < EE; ++e) te[e] = sBp[e];
    #pragma unroll
    for (int o = 0; o < OO; ++o) {
        const float ov = to_[o];
        const float4* wr = (const float4*)(sWp + o*EE);
        #pragma unroll
        for (int e4 = 0; e4 < EE/4; ++e4) {
            float4 w = wr[e4];
            te[4*e4+0] = fmaf(ov, w.x, te[4*e4+0]);
            te[4*e4+1] = fmaf(ov, w.y, te[4*e4+1]);
            te[4*e4+2] = fmaf(ov, w.z, te[4*e4+2]);
            te[4*e4+3] = fmaf(ov, w.w, te[4*e4+3]);
        }
    }

    float4* dst = (float4*)(tok + ((size_t)f*BB + (size_t)b)*EE);
    dst[0] = make_float4(te[0],  te[1],  te[2],  te[3]);
    dst[1] = make_float4(te[4],  te[5],  te[6],  te[7]);
    dst[2] = make_float4(te[8],  te[9],  te[10], te[11]);
    dst[3] = make_float4(te[12], te[13], te[14], te[15]);
}

// ---------------- Phase 2: qkv + attention + pool + final FC ----------------
#define KVPAD 260   // per-batch row stride (floats): 16*16 + 4 pad -> bank shift 4/batch

__global__ __launch_bounds__(256) void spinn_attn_kernel(
    const float* __restrict__ tok,
    const float* __restrict__ Wqkv, const float* __restrict__ bqkv,
    const float* __restrict__ Wo,   const float* __restrict__ bo,
    const float* __restrict__ Wf,   const float* __restrict__ bf,
    float* __restrict__ out)
{
    __shared__ __align__(16) float sWqkv[EE*48];
    __shared__ float sbqkv[48];
    __shared__ float sWo[EE*EE], sbo[EE], sWf[EE], sbf;
    __shared__ __align__(16) float kb[16*KVPAD];
    __shared__ __align__(16) float vb[16*KVPAD];

    const int t = threadIdx.x;
    if (t < 192) ((float4*)sWqkv)[t] = ((const float4*)Wqkv)[t];
    if (t < 48)  sbqkv[t] = bqkv[t];
    if (t < 64)  ((float4*)sWo)[t] = ((const float4*)Wo)[t];
    if (t < EE)  { sbo[t] = bo[t]; sWf[t] = Wf[t]; }
    if (t == 0)  sbf = bf[0];
    __syncthreads();

    const int f  = t & 15;        // token index (lane bits 0..3 -> butterfly stays in-group)
    const int bl = t >> 4;        // local batch
    const int b  = blockIdx.x * 16 + bl;

    float tokv[EE];
    {
        const float4* tp = (const float4*)(tok + ((size_t)f*BB + (size_t)b)*EE);
        float4 v0 = tp[0], v1 = tp[1], v2 = tp[2], v3 = tp[3];
        tokv[0]=v0.x; tokv[1]=v0.y; tokv[2]=v0.z; tokv[3]=v0.w;
        tokv[4]=v1.x; tokv[5]=v1.y; tokv[6]=v1.z; tokv[7]=v1.w;
        tokv[8]=v2.x; tokv[9]=v2.y; tokv[10]=v2.z; tokv[11]=v2.w;
        tokv[12]=v3.x; tokv[13]=v3.y; tokv[14]=v3.z; tokv[15]=v3.w;
    }

    // qkv = tok @ Wqkv + bqkv   (acc[0:16]=q, [16:32]=k, [32:48]=v)
    float acc[48];
    #pragma unroll
    for (int i = 0; i < 48; ++i) acc[i] = sbqkv[i];
    #pragma unroll
    for (int e = 0; e < EE; ++e) {
        const float tv = tokv[e];
        const float4* wr = (const float4*)(sWqkv + e*48);
        #pragma unroll
        for (int i4 = 0; i4 < 12; ++i4) {
            float4 w = wr[i4];
            acc[4*i4+0] = fmaf(tv, w.x, acc[4*i4+0]);
            acc[4*i4+1] = fmaf(tv, w.y, acc[4*i4+1]);
            acc[4*i4+2] = fmaf(tv, w.z, acc[4*i4+2]);
            acc[4*i4+3] = fmaf(tv, w.w, acc[4*i4+3]);
        }
    }

    {
        float4* kr = (float4*)(kb + bl*KVPAD + f*16);
        float4* vr = (float4*)(vb + bl*KVPAD + f*16);
        kr[0] = make_float4(acc[16], acc[17], acc[18], acc[19]);
        kr[1] = make_float4(acc[20], acc[21], acc[22], acc[23]);
        kr[2] = make_float4(acc[24], acc[25], acc[26], acc[27]);
        kr[3] = make_float4(acc[28], acc[29], acc[30], acc[31]);
        vr[0] = make_float4(acc[32], acc[33], acc[34], acc[35]);
        vr[1] = make_float4(acc[36], acc[37], acc[38], acc[39]);
        vr[2] = make_float4(acc[40], acc[41], acc[42], acc[43]);
        vr[3] = make_float4(acc[44], acc[45], acc[46], acc[47]);
    }
    __syncthreads();

    // scores (this thread's q row vs all k rows), scale 1/sqrt(E)=0.25
    float s[16];
    #pragma unroll
    for (int kk = 0; kk < 16; ++kk) {
        const float4* krow = (const float4*)(kb + bl*KVPAD + kk*16);
        float4 k0 = krow[0], k1 = krow[1], k2 = krow[2], k3 = krow[3];
        float d = acc[0]*k0.x + acc[1]*k0.y + acc[2]*k0.z + acc[3]*k0.w
                + acc[4]*k1.x + acc[5]*k1.y + acc[6]*k1.z + acc[7]*k1.w
                + acc[8]*k2.x + acc[9]*k2.y + acc[10]*k2.z + acc[11]*k2.w
                + acc[12]*k3.x + acc[13]*k3.y + acc[14]*k3.z + acc[15]*k3.w;
        s[kk] = d * 0.25f;
    }

    // stable softmax over own row
    float m = s[0];
    #pragma unroll
    for (int kk = 1; kk < 16; ++kk) m = fmaxf(m, s[kk]);
    float sum = 0.f;
    #pragma unroll
    for (int kk = 0; kk < 16; ++kk) { s[kk] = __expf(s[kk] - m); sum += s[kk]; }
    const float inv = 1.0f / sum;
    #pragma unroll
    for (int kk = 0; kk < 16; ++kk) s[kk] *= inv;

    // column sums of attention matrix across the 16 token-lanes (butterfly)
    #pragma unroll
    for (int kk = 0; kk < 16; ++kk) {
        float v = s[kk];
        v += __shfl_xor(v, 1); v += __shfl_xor(v, 2);
        v += __shfl_xor(v, 4); v += __shfl_xor(v, 8);
        s[kk] = v;   // = 16 * abar[kk], identical across the 16 lanes
    }

    // pooled_v[f] = sum_kk abar[kk] * v[kk][f]  (lane f reads column f of vb)
    float pvf = 0.f;
    #pragma unroll
    for (int kk = 0; kk < 16; ++kk) pvf = fmaf(s[kk], vb[bl*KVPAD + kk*16 + f], pvf);
    pvf *= 0.0625f;  // /16 from the mean

    // wof[f] = sum_e2 Wo[f][e2]*Wf[e2]; out = leaky(sum_f pooled_v[f]*wof[f] + sum bo*Wf + bf)
    float wof = 0.f;
    #pragma unroll
    for (int e2 = 0; e2 < EE; ++e2) wof = fmaf(sWo[f*16 + e2], sWf[e2], wof);

    float c = fmaf(pvf, wof, sbo[f]*sWf[f]);
    c += __shfl_xor(c, 1); c += __shfl_xor(c, 2);
    c += __shfl_xor(c, 4); c += __shfl_xor(c, 8);

    if (f == 0) {
        float r = c + sbf;
        out[b] = (r >= 0.f) ? r : 0.01f*r;
    }
}

extern "C" void kernel_launch(void* const* d_in, const int* in_sizes, int n_in,
                              void* d_out, int out_size, void* d_ws, size_t ws_size,
                              hipStream_t stream)
{
    const float* x    = (const float*)d_in[0];
    const float* W1   = (const float*)d_in[1];
    const float* b1   = (const float*)d_in[2];
    const float* W2   = (const float*)d_in[3];
    const float* b2   = (const float*)d_in[4];
    const float* W3   = (const float*)d_in[5];
    const float* b3   = (const float*)d_in[6];
    const float* Wp   = (const float*)d_in[7];
    const float* bp   = (const float*)d_in[8];
    const float* Wqkv = (const float*)d_in[9];
    const float* bqkv = (const float*)d_in[10];
    const float* Wo   = (const float*)d_in[11];
    const float* bo   = (const float*)d_in[12];
    const float* Wf   = (const float*)d_in[13];
    const float* bf   = (const float*)d_in[14];
    float* out = (float*)d_out;
    float* tok = (float*)d_ws;   // [F][B][E] fp32 = 32 MB scratch

    dim3 g1(BB/256, FF);
    spinn_subnet_kernel<<<g1, 256, 0, stream>>>(x, W1, b1, W2, b2, W3, b3, Wp, bp, tok);
    spinn_attn_kernel<<<BB/16, 256, 0, stream>>>(tok, Wqkv, bqkv, Wo, bo, Wf, bf, out);
}

// Round 2
// 214.678 us; speedup vs baseline: 1.1049x; 1.1049x over previous
//
#include <hip/hip_runtime.h>

#define BB 32768
#define FF 16
#define HH 64
#define OO 32
#define EE 16

// ---------------- Phase 1: per-feature subnets -> tok [F][B][E] ----------------
// All weights are wave-uniform (f = blockIdx.y, unrolled/uniform loop indices):
// read them directly from global so the compiler emits s_load -> SGPR broadcast,
// keeping the LDS pipe idle and the VALU fed (v_fmac v, s, v).
__global__ __launch_bounds__(256, 4) void spinn_subnet_kernel(
    const float* __restrict__ x,
    const float* __restrict__ W1, const float* __restrict__ b1,
    const float* __restrict__ W2, const float* __restrict__ b2,
    const float* __restrict__ W3, const float* __restrict__ b3,
    const float* __restrict__ Wp, const float* __restrict__ bp,
    float* __restrict__ tok)
{
    const int f = blockIdx.y;
    const int t = threadIdx.x;
    const int b = blockIdx.x * 256 + t;

    const float* __restrict__ w1  = W1 + f*HH;      // [64]   (W1[f,0,:])
    const float* __restrict__ bb1 = b1 + f*HH;
    const float* __restrict__ w2  = W2 + f*HH*HH;   // [64][64]
    const float* __restrict__ bb2 = b2 + f*HH;
    const float* __restrict__ w3  = W3 + f*HH*OO;   // [64][32]
    const float* __restrict__ bb3 = b3 + f*OO;

    const float xv = x[(size_t)b*FF + f];

    // ---- layer 1+2: h2 = b2 + sum_j leaky(x*w1[j]+b1[j]) * w2[j][:] ----
    float h2[HH];
    #pragma unroll
    for (int k = 0; k < HH; ++k) h2[k] = bb2[k];

    #pragma unroll 2
    for (int j = 0; j < HH; ++j) {       // rolled: hot loop stays in icache
        float h1 = fmaf(xv, w1[j], bb1[j]);
        h1 = (h1 >= 0.f) ? h1 : 0.01f*h1;
        #pragma unroll
        for (int k = 0; k < HH; ++k)
            h2[k] = fmaf(h1, w2[j*HH + k], h2[k]);   // SGPR weight operand
    }
    #pragma unroll
    for (int k = 0; k < HH; ++k) { float v = h2[k]; h2[k] = (v >= 0.f) ? v : 0.01f*v; }

    // ---- layer 3 (j fully unrolled: h2[j] must be statically indexed) ----
    float to_[OO];
    #pragma unroll
    for (int o = 0; o < OO; ++o) to_[o] = bb3[o];
    #pragma unroll
    for (int j = 0; j < HH; ++j) {
        const float hv = h2[j];
        #pragma unroll
        for (int o = 0; o < OO; ++o)
            to_[o] = fmaf(hv, w3[j*OO + o], to_[o]);
    }

    // ---- proj O->E (o fully unrolled: to_[o] statically indexed) ----
    float te[EE];
    #pragma unroll
    for (int e = 0; e < EE; ++e) te[e] = bp[e];
    #pragma unroll
    for (int o = 0; o < OO; ++o) {
        const float ov = to_[o];
        #pragma unroll
        for (int e = 0; e < EE; ++e)
            te[e] = fmaf(ov, Wp[o*EE + e], te[e]);
    }

    float4* dst = (float4*)(tok + ((size_t)f*BB + (size_t)b)*EE);
    dst[0] = make_float4(te[0],  te[1],  te[2],  te[3]);
    dst[1] = make_float4(te[4],  te[5],  te[6],  te[7]);
    dst[2] = make_float4(te[8],  te[9],  te[10], te[11]);
    dst[3] = make_float4(te[12], te[13], te[14], te[15]);
}

// ---------------- Phase 2: qkv + attention + pool + final FC ----------------
#define KVPAD 260   // floats per batch row: 256 + 4 pad; 1040 B stride (16B aligned, bank shift 4)

// Full-rate DPP butterfly sum over each aligned 16-lane group (replicated).
__device__ __forceinline__ float sum16(float v) {
    int i;
    i = __builtin_amdgcn_update_dpp(0, __float_as_int(v), 0xB1,  0xF, 0xF, true); v += __int_as_float(i); // xor 1 (quad_perm 1,0,3,2)
    i = __builtin_amdgcn_update_dpp(0, __float_as_int(v), 0x4E,  0xF, 0xF, true); v += __int_as_float(i); // xor 2 (quad_perm 2,3,0,1)
    i = __builtin_amdgcn_update_dpp(0, __float_as_int(v), 0x141, 0xF, 0xF, true); v += __int_as_float(i); // row_half_mirror: + other quad of 8-group
    i = __builtin_amdgcn_update_dpp(0, __float_as_int(v), 0x140, 0xF, 0xF, true); v += __int_as_float(i); // row_mirror: + other 8-group
    return v;
}

__global__ __launch_bounds__(256, 4) void spinn_attn_kernel(
    const float* __restrict__ tok,
    const float* __restrict__ Wqkv, const float* __restrict__ bqkv,
    const float* __restrict__ Wo,   const float* __restrict__ bo,
    const float* __restrict__ Wf,   const float* __restrict__ bf,
    float* __restrict__ out)
{
    __shared__ __align__(16) float kb[16*KVPAD];
    __shared__ __align__(16) float vb[16*KVPAD];

    const int t  = threadIdx.x;
    const int f  = t & 15;        // token index (in-wave 16-lane group)
    const int bl = t >> 4;        // local batch 0..15 (4 per wave -> regions are per-wave, no barrier needed)
    const int b  = blockIdx.x * 16 + bl;

    float tokv[EE];
    {
        const float4* tp = (const float4*)(tok + ((size_t)f*BB + (size_t)b)*EE);
        float4 v0 = tp[0], v1 = tp[1], v2 = tp[2], v3 = tp[3];
        tokv[0]=v0.x; tokv[1]=v0.y; tokv[2]=v0.z; tokv[3]=v0.w;
        tokv[4]=v1.x; tokv[5]=v1.y; tokv[6]=v1.z; tokv[7]=v1.w;
        tokv[8]=v2.x; tokv[9]=v2.y; tokv[10]=v2.z; tokv[11]=v2.w;
        tokv[12]=v3.x; tokv[13]=v3.y; tokv[14]=v3.z; tokv[15]=v3.w;
    }

    // qkv = tok @ Wqkv + bqkv (weights wave-uniform -> s_load)
    float acc[48];
    #pragma unroll
    for (int i = 0; i < 48; ++i) acc[i] = bqkv[i];
    #pragma unroll
    for (int e = 0; e < EE; ++e) {
        const float tv = tokv[e];
        #pragma unroll
        for (int i = 0; i < 48; ++i)
            acc[i] = fmaf(tv, Wqkv[e*48 + i], acc[i]);
    }

    // park k,v rows in LDS (intra-wave transpose; no cross-wave sharing)
    {
        float4* kr = (float4*)(kb + bl*KVPAD + f*16);
        float4* vr = (float4*)(vb + bl*KVPAD + f*16);
        kr[0] = make_float4(acc[16], acc[17], acc[18], acc[19]);
        kr[1] = make_float4(acc[20], acc[21], acc[22], acc[23]);
        kr[2] = make_float4(acc[24], acc[25], acc[26], acc[27]);
        kr[3] = make_float4(acc[28], acc[29], acc[30], acc[31]);
        vr[0] = make_float4(acc[32], acc[33], acc[34], acc[35]);
        vr[1] = make_float4(acc[36], acc[37], acc[38], acc[39]);
        vr[2] = make_float4(acc[40], acc[41], acc[42], acc[43]);
        vr[3] = make_float4(acc[44], acc[45], acc[46], acc[47]);
    }

    // scores: own q row vs all 16 k rows, scale 1/sqrt(16)=0.25
    float s[16];
    #pragma unroll
    for (int kk = 0; kk < 16; ++kk) {
        const float4* krow = (const float4*)(kb + bl*KVPAD + kk*16);
        float4 k0 = krow[0], k1 = krow[1], k2 = krow[2], k3 = krow[3];
        float d = acc[0]*k0.x + acc[1]*k0.y + acc[2]*k0.z + acc[3]*k0.w
                + acc[4]*k1.x + acc[5]*k1.y + acc[6]*k1.z + acc[7]*k1.w
                + acc[8]*k2.x + acc[9]*k2.y + acc[10]*k2.z + acc[11]*k2.w
                + acc[12]*k3.x + acc[13]*k3.y + acc[14]*k3.z + acc[15]*k3.w;
        s[kk] = d * 0.25f;
    }

    // stable softmax over own row
    float m = s[0];
    #pragma unroll
    for (int kk = 1; kk < 16; ++kk) m = fmaxf(m, s[kk]);
    float sum = 0.f;
    #pragma unroll
    for (int kk = 0; kk < 16; ++kk) { s[kk] = __expf(s[kk] - m); sum += s[kk]; }
    const float inv = 1.0f / sum;
    #pragma unroll
    for (int kk = 0; kk < 16; ++kk) s[kk] *= inv;

    // column sums of the attention matrix across the 16 token-lanes (DPP, full rate)
    #pragma unroll
    for (int kk = 0; kk < 16; ++kk) s[kk] = sum16(s[kk]);   // = 16*abar[kk], replicated

    // pooled_v[f] = sum_kk abar[kk] * v[kk][f]
    float pvf = 0.f;
    #pragma unroll
    for (int kk = 0; kk < 16; ++kk) pvf = fmaf(s[kk], vb[bl*KVPAD + kk*16 + f], pvf);
    pvf *= 0.0625f;   // /16 from the mean

    // wof[f] = Wo[f][:] . Wf  (Wo row per-lane vector load, Wf uniform -> SGPR)
    float wof = 0.f;
    {
        const float4* wr = (const float4*)(Wo + f*EE);
        float4 w0 = wr[0], w1 = wr[1], w2 = wr[2], w3 = wr[3];
        wof = w0.x*Wf[0] + w0.y*Wf[1] + w0.z*Wf[2] + w0.w*Wf[3]
            + w1.x*Wf[4] + w1.y*Wf[5] + w1.z*Wf[6] + w1.w*Wf[7]
            + w2.x*Wf[8] + w2.y*Wf[9] + w2.z*Wf[10] + w2.w*Wf[11]
            + w3.x*Wf[12] + w3.y*Wf[13] + w3.z*Wf[14] + w3.w*Wf[15];
    }

    float c = fmaf(pvf, wof, bo[f]*Wf[f]);
    c = sum16(c);

    if (f == 0) {
        float r = c + bf[0];
        out[b] = (r >= 0.f) ? r : 0.01f*r;
    }
}

extern "C" void kernel_launch(void* const* d_in, const int* in_sizes, int n_in,
                              void* d_out, int out_size, void* d_ws, size_t ws_size,
                              hipStream_t stream)
{
    const float* x    = (const float*)d_in[0];
    const float* W1   = (const float*)d_in[1];
    const float* b1   = (const float*)d_in[2];
    const float* W2   = (const float*)d_in[3];
    const float* b2   = (const float*)d_in[4];
    const float* W3   = (const float*)d_in[5];
    const float* b3   = (const float*)d_in[6];
    const float* Wp   = (const float*)d_in[7];
    const float* bp   = (const float*)d_in[8];
    const float* Wqkv = (const float*)d_in[9];
    const float* bqkv = (const float*)d_in[10];
    const float* Wo   = (const float*)d_in[11];
    const float* bo   = (const float*)d_in[12];
    const float* Wf   = (const float*)d_in[13];
    const float* bf   = (const float*)d_in[14];
    float* out = (float*)d_out;
    float* tok = (float*)d_ws;   // [F][B][E] fp32 = 32 MB scratch

    dim3 g1(BB/256, FF);
    spinn_subnet_kernel<<<g1, 256, 0, stream>>>(x, W1, b1, W2, b2, W3, b3, Wp, bp, tok);
    spinn_attn_kernel<<<BB/16, 256, 0, stream>>>(tok, Wqkv, bqkv, Wo, bo, Wf, bf, out);
}